// Round 2
// baseline (263.298 us; speedup 1.0000x reference)
//
#include <hip/hip_runtime.h>

// DMoE (PLE/CGC) fused kernel for MI355X (gfx950).
// B=32768, D_IN=256, H=128, N_TASK=2, N_EXP=4, N_SHARE=4.
//
// R2: latency-bound fix. BM 64->32 (grid 512->1024, 4 blocks/CU schedulable),
// A-fragments held in registers across all 12 experts (they don't depend on
// the expert), gates stored transposed for ds_read_b128 epilogue loads,
// prep kernel made coalesced via LDS tile transpose.

#define BM 32

typedef __attribute__((ext_vector_type(8))) short short8;   // 8 x bf16 frag
typedef __attribute__((ext_vector_type(4))) float float4v;  // C/D frag

__device__ __forceinline__ unsigned short f2bf(float f) {
  unsigned u = __builtin_bit_cast(unsigned, f);
  u += 0x7FFFu + ((u >> 16) & 1u);   // round-to-nearest-even
  return (unsigned short)(u >> 16);
}

// ---------------------------------------------------------------------------
// Prep: build WT (bf16) in workspace.
//   WT[e][h][k], e = 0..3 shared, 4..11 task (t*4+ee), each 128(h) x 256(k).
//   Then WTg[n][k], n = t*8+g, 16x256, at offset 12*32768.
// Blocks 0..95: expert tiles (e, kt, ht) 64x64 via LDS transpose. Block 96: gates.
__global__ __launch_bounds__(256)
void prep_kernel(const float* __restrict__ Ws,
                 const float* __restrict__ Wt,
                 const float* __restrict__ Wg,
                 unsigned short* __restrict__ WT) {
  int bid = blockIdx.x;
  int tid = threadIdx.x;
  if (bid < 96) {
    __shared__ float tile[64][65];
    int e  = bid >> 3;
    int kt = (bid >> 1) & 3;   // k-tile of 64 (D_IN=256)
    int ht = bid & 1;          // h-tile of 64 (H=128)
    const float* src = (e < 4) ? Ws + ((size_t)e << 15)
                               : Wt + ((size_t)(e - 4) << 15);
    int m = tid & 15, n = tid >> 4;   // m: h-quad, n: 0..15
    // coalesced read: src[k][h], 4 consecutive h per lane
    #pragma unroll
    for (int i = 0; i < 4; ++i) {
      int kl = i * 16 + n;
      float4 v = *(const float4*)&src[(size_t)(kt * 64 + kl) * 128 + ht * 64 + m * 4];
      tile[kl][m * 4 + 0] = v.x;
      tile[kl][m * 4 + 1] = v.y;
      tile[kl][m * 4 + 2] = v.z;
      tile[kl][m * 4 + 3] = v.w;
    }
    __syncthreads();
    // coalesced write: WT[e][h][k], 4 consecutive k per lane
    #pragma unroll
    for (int i = 0; i < 4; ++i) {
      int hl = i * 16 + n;
      ushort4 o;
      o.x = f2bf(tile[m * 4 + 0][hl]);
      o.y = f2bf(tile[m * 4 + 1][hl]);
      o.z = f2bf(tile[m * 4 + 2][hl]);
      o.w = f2bf(tile[m * 4 + 3][hl]);
      *(ushort4*)&WT[(size_t)e * 32768 + (size_t)(ht * 64 + hl) * 256 + kt * 64 + m * 4] = o;
    }
  } else {
    // gate weights: WTg[n][k] = Wg[t][k][g], n = t*8+g  (tiny: 16 KB)
    unsigned short* WTg = WT + 12 * 32768;
    #pragma unroll
    for (int it = 0; it < 16; ++it) {
      int j = it * 256 + tid;
      int n = j >> 8, k = j & 255;
      int t = n >> 3, g = n & 7;
      WTg[j] = f2bf(Wg[(size_t)(t * 256 + k) * 8 + g]);
    }
  }
}

// ---------------------------------------------------------------------------
__global__ __launch_bounds__(256, 3)
void dmoe_main(const float* __restrict__ x,
               const unsigned short* __restrict__ WT,
               const float* __restrict__ b_share,
               const float* __restrict__ b_task,
               const float* __restrict__ b_gate,
               float* __restrict__ out) {
  __shared__ unsigned short xs[BM * 264];   // 16.9 KB, padded rows
  __shared__ float gatesT[16 * 36];         // [gate-col][row], stride 36 (16B-aligned quads)

  const int tid  = threadIdx.x;
  const int lane = tid & 63;
  const int wave = tid >> 6;       // 0..3
  const int col  = lane & 15;      // MFMA m/n index
  const int quad = lane >> 4;      // 0..3
  const int blk  = blockIdx.x;

  // ---- stage x tile -> LDS bf16 (row stride 264 elems) ----
  {
    const float4* x4 = (const float4*)(x + (size_t)blk * BM * 256);
    #pragma unroll
    for (int it = 0; it < 8; ++it) {
      int i   = it * 256 + tid;    // 0..2047
      int row = i >> 6;
      int c4  = i & 63;
      float4 v = x4[i];
      unsigned lo = (unsigned)f2bf(v.x) | ((unsigned)f2bf(v.y) << 16);
      unsigned hi = (unsigned)f2bf(v.z) | ((unsigned)f2bf(v.w) << 16);
      unsigned long long p = ((unsigned long long)hi << 32) | lo;
      *(unsigned long long*)&xs[row * 264 + c4 * 4] = p;
    }
  }
  __syncthreads();

  // ---- gates: waves 0,1 compute rows [16w,16w+16), 16 logit cols ----
  if (wave < 2) {
    const unsigned short* wg = WT + 12 * 32768;   // [16][256]
    short8 ga[8], gb[8];
    const unsigned short* ap = &xs[(wave * 16 + col) * 264 + quad * 8];
    const unsigned short* bp = wg + col * 256 + quad * 8;
    #pragma unroll
    for (int kk = 0; kk < 8; ++kk) {
      ga[kk] = *(const short8*)(ap + kk * 32);
      gb[kk] = *(const short8*)(bp + kk * 32);
    }
    float4v acc = {0.f, 0.f, 0.f, 0.f};
    #pragma unroll
    for (int kk = 0; kk < 8; ++kk)
      acc = __builtin_amdgcn_mfma_f32_16x16x32_bf16(ga[kk], gb[kk], acc, 0, 0, 0);
    float bg = b_gate[col];
    #pragma unroll
    for (int r = 0; r < 4; ++r) {
      float v = acc[r] + bg;
      // softmax over 8 gate cols (lanes differing in col bits 0..2)
      float m = v;
      m = fmaxf(m, __shfl_xor(m, 1));
      m = fmaxf(m, __shfl_xor(m, 2));
      m = fmaxf(m, __shfl_xor(m, 4));
      float p = __expf(v - m);
      float s = p;
      s += __shfl_xor(s, 1);
      s += __shfl_xor(s, 2);
      s += __shfl_xor(s, 4);
      int row = wave * 16 + quad * 4 + r;
      gatesT[col * 36 + row] = p / s;
    }
  }
  __syncthreads();

  // ---- A-fragments: resident across all experts (expert-independent) ----
  short8 a[2][8];
  #pragma unroll
  for (int c = 0; c < 2; ++c) {
    const unsigned short* ap = &xs[(c * 16 + col) * 264 + quad * 8];
    #pragma unroll
    for (int kk = 0; kk < 8; ++kk)
      a[c][kk] = *(const short8*)(ap + kk * 32);
  }

  // ---- main loop: 12 experts, wave owns h-slice [32*wave, 32*wave+32) ----
  const int hb = wave * 32;
  float tw[2][2][2][4];   // [task][chunk][ntile][r]
  #pragma unroll
  for (int t = 0; t < 2; ++t)
    #pragma unroll
    for (int c = 0; c < 2; ++c)
      #pragma unroll
      for (int nt = 0; nt < 2; ++nt)
        #pragma unroll
        for (int r = 0; r < 4; ++r)
          tw[t][c][nt][r] = 0.f;

  #pragma unroll 1
  for (int e = 0; e < 12; ++e) {
    short8 bf0[8], bf1[8];
    const unsigned short* bp0 = WT + (size_t)e * 32768 + (size_t)(hb + col) * 256 + quad * 8;
    const unsigned short* bp1 = bp0 + 16 * 256;
    #pragma unroll
    for (int kk = 0; kk < 8; ++kk) {
      bf0[kk] = *(const short8*)(bp0 + kk * 32);
      bf1[kk] = *(const short8*)(bp1 + kk * 32);
    }
    const float* bptr = (e < 4) ? (b_share + e * 128) : (b_task + (e - 4) * 128);
    float bias0 = bptr[hb + col];
    float bias1 = bptr[hb + 16 + col];

    #pragma unroll
    for (int c = 0; c < 2; ++c) {
      float4v acc0 = {0.f, 0.f, 0.f, 0.f};
      float4v acc1 = {0.f, 0.f, 0.f, 0.f};
      #pragma unroll
      for (int kk = 0; kk < 8; ++kk) {
        acc0 = __builtin_amdgcn_mfma_f32_16x16x32_bf16(a[c][kk], bf0[kk], acc0, 0, 0, 0);
        acc1 = __builtin_amdgcn_mfma_f32_16x16x32_bf16(a[c][kk], bf1[kk], acc1, 0, 0, 0);
      }
      int rbase = c * 16 + quad * 4;
      if (e < 4) {
        float4 g0 = *(const float4*)&gatesT[e * 36 + rbase];        // task 0
        float4 g1 = *(const float4*)&gatesT[(8 + e) * 36 + rbase];  // task 1
        #pragma unroll
        for (int r = 0; r < 4; ++r) {
          float v0 = fmaxf(acc0[r] + bias0, 0.f);
          float v1 = fmaxf(acc1[r] + bias1, 0.f);
          float ga = ((const float*)&g0)[r];
          float gb = ((const float*)&g1)[r];
          tw[0][c][0][r] += ga * v0;
          tw[0][c][1][r] += ga * v1;
          tw[1][c][0][r] += gb * v0;
          tw[1][c][1][r] += gb * v1;
        }
      } else {
        int t = (e >= 8);
        int gcol = t ? (e + 4) : e;
        float4 g = *(const float4*)&gatesT[gcol * 36 + rbase];
        #pragma unroll
        for (int r = 0; r < 4; ++r) {
          float v0 = fmaxf(acc0[r] + bias0, 0.f);
          float v1 = fmaxf(acc1[r] + bias1, 0.f);
          float gv = ((const float*)&g)[r];
          tw[t][c][0][r] += gv * v0;
          tw[t][c][1][r] += gv * v1;
        }
      }
    }
  }

  // ---- write towers: out[t][row][h], t-stride = 32768*128 = 1<<22 ----
  #pragma unroll
  for (int t = 0; t < 2; ++t)
    #pragma unroll
    for (int c = 0; c < 2; ++c)
      #pragma unroll
      for (int nt = 0; nt < 2; ++nt)
        #pragma unroll
        for (int r = 0; r < 4; ++r) {
          int row = blk * BM + c * 16 + quad * 4 + r;
          int h   = hb + nt * 16 + col;
          out[((size_t)t << 22) + (size_t)row * 128 + h] = tw[t][c][nt][r];
        }
}

// ---------------------------------------------------------------------------
extern "C" void kernel_launch(void* const* d_in, const int* in_sizes, int n_in,
                              void* d_out, int out_size, void* d_ws, size_t ws_size,
                              hipStream_t stream) {
  const float* x       = (const float*)d_in[0];
  const float* W_share = (const float*)d_in[1];
  const float* b_share = (const float*)d_in[2];
  const float* W_task  = (const float*)d_in[3];
  const float* b_task  = (const float*)d_in[4];
  const float* W_gate  = (const float*)d_in[5];
  const float* b_gate  = (const float*)d_in[6];
  float* out = (float*)d_out;
  unsigned short* WT = (unsigned short*)d_ws;   // 397312 bf16 = 794624 B

  prep_kernel<<<97, 256, 0, stream>>>(W_share, W_task, W_gate, WT);
  dmoe_main<<<1024, 256, 0, stream>>>(x, WT, b_share, b_task, b_gate, out);
}

// Round 3
// 177.902 us; speedup vs baseline: 1.4800x; 1.4800x over previous
//
#include <hip/hip_runtime.h>

// DMoE (PLE/CGC) fused kernel for MI355X (gfx950).
// B=32768, D_IN=256, H=128, N_TASK=2, N_EXP=4, N_SHARE=4.
//
// R3: async-staged expert pipeline.
//  - prep: weights -> WT bf16, h-major, k-stride padded to 264 elems (pad in
//    the GLOBAL image so contiguous global_load_lds staging preserves it;
//    264-elem stride => 2-way-only LDS bank aliasing = free).
//  - main: 256 blocks x 512 thr (1 block/CU, LDS ~146 KB). A-frags (x) live
//    in VGPRs across all 12 experts. Expert weights staged to LDS via
//    global_load_lds dwordx4, double-buffered across TWO named LDS arrays
//    (Bs0/Bs1) with the expert loop unrolled by 2 so buffer choice is
//    compile-time and alias analysis keeps the async loads in flight
//    across the barrier. One barrier per expert; each stage has a full
//    compute phase to land.

#define ROWSTRIDE 264                        // 256 data + 8 pad (bf16 elems)
#define EXPERT_USHORTS (128 * ROWSTRIDE)     // 33792
#define EXPERT_BYTES   (EXPERT_USHORTS * 2)  // 67584 = 8 waves * 8448
#define WAVE_SHARE     8448                  // bytes staged per wave
#define WTG_USHORTS    (16 * ROWSTRIDE)      // 4224

typedef __attribute__((ext_vector_type(8))) short short8;   // 8 x bf16
typedef __attribute__((ext_vector_type(4))) float float4v;  // MFMA C/D

__device__ __forceinline__ unsigned short f2bf(float f) {
  unsigned u = __builtin_bit_cast(unsigned, f);
  u += 0x7FFFu + ((u >> 16) & 1u);   // round-to-nearest-even
  return (unsigned short)(u >> 16);
}

typedef const __attribute__((address_space(1))) unsigned int gu32;
typedef __attribute__((address_space(3))) unsigned int lu32;

__device__ __forceinline__ void gl_lds16(const void* g, void* l) {
  __builtin_amdgcn_global_load_lds((gu32*)g, (lu32*)l, 16, 0, 0);
}
__device__ __forceinline__ void gl_lds4(const void* g, void* l) {
  __builtin_amdgcn_global_load_lds((gu32*)g, (lu32*)l, 4, 0, 0);
}

// stage one expert tile (67584 B) : wave w copies bytes [w*8448, (w+1)*8448)
__device__ __forceinline__ void stage_expert(const unsigned short* WT, int e,
                                             unsigned short* dst, int w, int lane) {
  const char* g = (const char*)WT + (size_t)e * EXPERT_BYTES + w * WAVE_SHARE;
  char* l = (char*)dst + w * WAVE_SHARE;
  #pragma unroll
  for (int i = 0; i < 8; ++i)
    gl_lds16(g + i * 1024 + lane * 16, l + i * 1024);
  gl_lds4(g + 8192 + lane * 4, l + 8192);   // 256 B remainder
}

// ---------------------------------------------------------------------------
// Prep: WT[e] padded tiles (12 x 128 x 264 bf16) + WTg (16 x 264) at the end.
__global__ __launch_bounds__(256)
void prep_kernel(const float* __restrict__ Ws,
                 const float* __restrict__ Wt,
                 const float* __restrict__ Wg,
                 unsigned short* __restrict__ WT) {
  int bid = blockIdx.x;
  int tid = threadIdx.x;
  if (bid < 96) {
    __shared__ float tile[64][65];
    int e  = bid >> 3;
    int kt = (bid >> 1) & 3;   // k-tile of 64
    int ht = bid & 1;          // h-tile of 64
    const float* src = (e < 4) ? Ws + ((size_t)e << 15)
                               : Wt + ((size_t)(e - 4) << 15);
    int m = tid & 15, n = tid >> 4;
    #pragma unroll
    for (int i = 0; i < 4; ++i) {   // coalesced read of src[k][h]
      int kl = i * 16 + n;
      float4 v = *(const float4*)&src[(size_t)(kt * 64 + kl) * 128 + ht * 64 + m * 4];
      tile[kl][m * 4 + 0] = v.x;
      tile[kl][m * 4 + 1] = v.y;
      tile[kl][m * 4 + 2] = v.z;
      tile[kl][m * 4 + 3] = v.w;
    }
    __syncthreads();
    #pragma unroll
    for (int i = 0; i < 4; ++i) {   // coalesced write of WT[e][h][k], stride 264
      int hl = i * 16 + n;
      ushort4 o;
      o.x = f2bf(tile[m * 4 + 0][hl]);
      o.y = f2bf(tile[m * 4 + 1][hl]);
      o.z = f2bf(tile[m * 4 + 2][hl]);
      o.w = f2bf(tile[m * 4 + 3][hl]);
      *(ushort4*)&WT[(size_t)e * EXPERT_USHORTS + (size_t)(ht * 64 + hl) * ROWSTRIDE
                     + kt * 64 + m * 4] = o;
    }
  } else {
    // gate weights WTg[n][264], n = t*8+g; plus zero the expert row-pads
    unsigned short* WTg = WT + 12 * EXPERT_USHORTS;
    for (int idx = tid; idx < WTG_USHORTS; idx += 256) {
      int n = idx / ROWSTRIDE, c = idx - n * ROWSTRIDE;
      int t = n >> 3, g = n & 7;
      WTg[idx] = (c < 256) ? f2bf(Wg[(size_t)(t * 256 + c) * 8 + g]) : (unsigned short)0;
    }
    for (int j = tid; j < 12 * 128; j += 256) {
      int e = j >> 7, h = j & 127;
      unsigned short* p = WT + (size_t)e * EXPERT_USHORTS + (size_t)h * ROWSTRIDE + 256;
      #pragma unroll
      for (int q = 0; q < 8; ++q) p[q] = 0;
    }
  }
}

// ---------------------------------------------------------------------------
__global__ __launch_bounds__(512, 2)
void dmoe_main(const float* __restrict__ x,
               const unsigned short* __restrict__ WT,
               const float* __restrict__ b_share,
               const float* __restrict__ b_task,
               const float* __restrict__ b_gate,
               float* __restrict__ out) {
  __shared__ unsigned short Bs0[EXPERT_USHORTS];   // 67584 B
  __shared__ unsigned short Bs1[EXPERT_USHORTS];   // 67584 B
  __shared__ float gatesT[16 * 132];               // 8448 B
  __shared__ float biasLds[12 * 128];              // 6144 B

  const int tid  = threadIdx.x;
  const int lane = tid & 63;
  const int w    = tid >> 6;    // wave 0..7
  const int col  = lane & 15;
  const int quad = lane >> 4;
  const int mg   = w >> 2;      // m-group: rows [mg*64, mg*64+64)
  const int ng   = w & 3;       // n-group: h    [ng*32, ng*32+32)
  const int blk  = blockIdx.x;

  // ---- prologue staging (async): WTg -> Bs1, expert 0 -> Bs0 ----
  {
    const char* wg = (const char*)(WT + 12 * EXPERT_USHORTS);
    gl_lds16(wg + w * 1024 + lane * 16, (char*)Bs1 + w * 1024);
    if (w == 0) gl_lds4(wg + 8192 + lane * 4, (char*)Bs1 + 8192);
  }
  stage_expert(WT, 0, Bs0, w, lane);

  // biases -> LDS
  for (int i = tid; i < 1536; i += 512)
    biasLds[i] = (i < 512) ? b_share[i] : b_task[i - 512];

  float bg = b_gate[col];

  // ---- A-fragments: 4 m-tiles x 8 k-steps resident (rows mg*64+mt*16+col)
  short8 A[4][8];
  {
    const float* xb = x + ((size_t)blk * 128 + mg * 64 + col) * 256 + quad * 8;
    #pragma unroll
    for (int mt = 0; mt < 4; ++mt) {
      const float* xr = xb + (size_t)mt * 16 * 256;
      #pragma unroll
      for (int k = 0; k < 8; ++k) {
        float4 u = *(const float4*)(xr + k * 32);
        float4 v = *(const float4*)(xr + k * 32 + 4);
        short8 fr;
        fr[0] = (short)f2bf(u.x); fr[1] = (short)f2bf(u.y);
        fr[2] = (short)f2bf(u.z); fr[3] = (short)f2bf(u.w);
        fr[4] = (short)f2bf(v.x); fr[5] = (short)f2bf(v.y);
        fr[6] = (short)f2bf(v.z); fr[7] = (short)f2bf(v.w);
        A[mt][k] = fr;
      }
    }
  }
  __syncthreads();   // WTg, expert0, biases all landed (vmcnt+lgkm drain)

  // ---- gates: every wave computes its m-group's 64 rows (all 16 logits);
  //      ng==0 waves write. A stays compile-time indexed.
  #pragma unroll
  for (int mt = 0; mt < 4; ++mt) {
    float4v ag = {0.f, 0.f, 0.f, 0.f};
    #pragma unroll
    for (int k = 0; k < 8; ++k) {
      short8 bfr = *(const short8*)((const char*)Bs1 + col * 528 + k * 64 + quad * 16);
      ag = __builtin_amdgcn_mfma_f32_16x16x32_bf16(A[mt][k], bfr, ag, 0, 0, 0);
    }
    #pragma unroll
    for (int r = 0; r < 4; ++r) {
      float vlog = ag[r] + bg;
      float m = vlog;
      m = fmaxf(m, __shfl_xor(m, 1));
      m = fmaxf(m, __shfl_xor(m, 2));
      m = fmaxf(m, __shfl_xor(m, 4));
      float p = __expf(vlog - m);
      float s = p;
      s += __shfl_xor(s, 1);
      s += __shfl_xor(s, 2);
      s += __shfl_xor(s, 4);
      if (ng == 0)
        gatesT[col * 132 + mg * 64 + mt * 16 + quad * 4 + r] = p / s;
    }
  }
  __syncthreads();   // gatesT visible; Bs1 free
  stage_expert(WT, 1, Bs1, w, lane);   // lands by the first in-loop barrier

  // ---- accumulators ----
  float tw[2][4][2][4];
  #pragma unroll
  for (int t = 0; t < 2; ++t)
    #pragma unroll
    for (int mt = 0; mt < 4; ++mt)
      #pragma unroll
      for (int nt = 0; nt < 2; ++nt)
        #pragma unroll
        for (int r = 0; r < 4; ++r)
          tw[t][mt][nt][r] = 0.f;

  const int hbase = ng * 32;

  // ---- expert loop, unrolled x2 so Bs0/Bs1 are distinct named objects ----
  #pragma unroll 1
  for (int ep = 0; ep < 6; ++ep) {
    #pragma unroll
    for (int half = 0; half < 2; ++half) {
      const int e = 2 * ep + half;
      const unsigned short* Bb = half ? Bs1 : Bs0;
      float b0 = biasLds[e * 128 + hbase + col];
      float b1 = biasLds[e * 128 + hbase + 16 + col];
      #pragma unroll
      for (int nt = 0; nt < 2; ++nt) {
        const char* bbase = (const char*)Bb + (hbase + nt * 16 + col) * 528 + quad * 16;
        float4v acc[4];
        #pragma unroll
        for (int mt = 0; mt < 4; ++mt) acc[mt] = (float4v){0.f, 0.f, 0.f, 0.f};
        #pragma unroll
        for (int k = 0; k < 8; ++k) {
          short8 bfr = *(const short8*)(bbase + k * 64);
          acc[0] = __builtin_amdgcn_mfma_f32_16x16x32_bf16(A[0][k], bfr, acc[0], 0, 0, 0);
          acc[1] = __builtin_amdgcn_mfma_f32_16x16x32_bf16(A[1][k], bfr, acc[1], 0, 0, 0);
          acc[2] = __builtin_amdgcn_mfma_f32_16x16x32_bf16(A[2][k], bfr, acc[2], 0, 0, 0);
          acc[3] = __builtin_amdgcn_mfma_f32_16x16x32_bf16(A[3][k], bfr, acc[3], 0, 0, 0);
        }
        float bb = nt ? b1 : b0;
        if (e < 4) {            // shared expert: feeds both tasks
          #pragma unroll
          for (int mt = 0; mt < 4; ++mt) {
            int rb = mg * 64 + mt * 16 + quad * 4;
            float4 g0 = *(const float4*)&gatesT[e * 132 + rb];
            float4 g1 = *(const float4*)&gatesT[(8 + e) * 132 + rb];
            #pragma unroll
            for (int r = 0; r < 4; ++r) {
              float v = fmaxf(acc[mt][r] + bb, 0.f);
              tw[0][mt][nt][r] += ((const float*)&g0)[r] * v;
              tw[1][mt][nt][r] += ((const float*)&g1)[r] * v;
            }
          }
        } else {                // task expert
          const int t  = (e >= 8);
          const int gc = t ? e + 4 : e;
          #pragma unroll
          for (int mt = 0; mt < 4; ++mt) {
            int rb = mg * 64 + mt * 16 + quad * 4;
            float4 g = *(const float4*)&gatesT[gc * 132 + rb];
            #pragma unroll
            for (int r = 0; r < 4; ++r) {
              float v = fmaxf(acc[mt][r] + bb, 0.f);
              tw[t][mt][nt][r] += ((const float*)&g)[r] * v;
            }
          }
        }
      }
      __syncthreads();          // all waves done reading this buffer
      if (e + 2 < 12) {
        // refill the buffer just consumed; lands during the next compute
        if (half == 0) stage_expert(WT, e + 2, Bs0, w, lane);
        else           stage_expert(WT, e + 2, Bs1, w, lane);
      }
    }
  }

  // ---- write towers: out[t][row][h]; nt innermost so the two 64B halves of
  //      each 128B line are stored back-to-back ----
  #pragma unroll
  for (int t = 0; t < 2; ++t)
    #pragma unroll
    for (int mt = 0; mt < 4; ++mt)
      #pragma unroll
      for (int r = 0; r < 4; ++r) {
        size_t row = (size_t)blk * 128 + mg * 64 + mt * 16 + quad * 4 + r;
        float* op = out + ((size_t)t << 22) + row * 128 + hbase;
        op[col]      = tw[t][mt][0][r];
        op[16 + col] = tw[t][mt][1][r];
      }
}

// ---------------------------------------------------------------------------
extern "C" void kernel_launch(void* const* d_in, const int* in_sizes, int n_in,
                              void* d_out, int out_size, void* d_ws, size_t ws_size,
                              hipStream_t stream) {
  const float* x       = (const float*)d_in[0];
  const float* W_share = (const float*)d_in[1];
  const float* b_share = (const float*)d_in[2];
  const float* W_task  = (const float*)d_in[3];
  const float* b_task  = (const float*)d_in[4];
  const float* W_gate  = (const float*)d_in[5];
  const float* b_gate  = (const float*)d_in[6];
  float* out = (float*)d_out;
  unsigned short* WT = (unsigned short*)d_ws;   // 12*33792 + 4224 ushorts = 819456 B

  prep_kernel<<<97, 256, 0, stream>>>(W_share, W_task, W_gate, WT);
  dmoe_main<<<256, 512, 0, stream>>>(x, WT, b_share, b_task, b_gate, out);
}

// Round 4
// 171.540 us; speedup vs baseline: 1.5349x; 1.0371x over previous
//
#include <hip/hip_runtime.h>

// DMoE (PLE/CGC) fused kernel for MI355X (gfx950).
// B=32768, D_IN=256, H=128, N_TASK=2, N_EXP=4, N_SHARE=4.
//
// R4: occupancy + stall attack.
//  - t-split: block computes ONE task (8 experts: 4 shared + its 4).
//    grid = 512 row-tiles x 2 tasks = 1024 blocks, 256 thr (4 waves).
//  - 3 blocks/CU (launch_bounds(256,3), VGPR<=170, LDS 43 KB/block).
//    256-thr blocks -> 1 wave/SIMD each -> 3 co-resident blocks give each
//    SIMD 3 waves with INDEPENDENT barriers.
//  - weights staged in k-split units (128h x 64k, rows padded to 72 elems),
//    double-buffered Bs0/Bs1 (buffer = kq&1, compile-time), staged via
//    global->VGPR->ds_write with loads issued a full compute phase early
//    (no global_load_lds -- suspected issue-serialization in R3).
//  - per-block expert-order rotation ((blk>>3)&7) to spread the L2
//    broadcast of the shared weight image across 8 distinct regions.
//  - A-fragments resident in VGPRs (64), accumulators acc 32 + tw 32.

typedef __attribute__((ext_vector_type(8))) short short8;   // 8 x bf16
typedef __attribute__((ext_vector_type(4))) float float4v;  // MFMA C/D

#define UNIT_B   18432            // staged unit: 128 rows x 144 B
#define ROW_B    144              // 72 bf16 elems (64 data + 8 pad)
#define WAVE_B   4608             // UNIT_B / 4 waves
#define WGT_OFF  442368           // ushort offset of WgT: 12*4*18432/2

__device__ __forceinline__ unsigned short f2bf(float f) {
  unsigned u = __builtin_bit_cast(unsigned, f);
  u += 0x7FFFu + ((u >> 16) & 1u);   // round-to-nearest-even
  return (unsigned short)(u >> 16);
}

__device__ __forceinline__ int slot2e(int sr, int t) {
  return (sr < 4) ? sr : 4 + t * 4 + (sr - 4);
}

// ---------------------------------------------------------------------------
// Prep: WT2[e][kq][128h][72k] bf16 (k-split padded units) + WgT[16][256].
__global__ __launch_bounds__(256)
void prep_kernel(const float* __restrict__ Ws,
                 const float* __restrict__ Wt,
                 const float* __restrict__ Wg,
                 unsigned short* __restrict__ WT2) {
  int bid = blockIdx.x;
  int tid = threadIdx.x;
  if (bid < 96) {
    __shared__ float tile[64][65];
    int e  = bid >> 3;
    int kt = (bid >> 1) & 3;   // k-tile / kq
    int ht = bid & 1;          // h-half
    const float* src = (e < 4) ? Ws + ((size_t)e << 15)
                               : Wt + ((size_t)(e - 4) << 15);
    int m = tid & 15, n = tid >> 4;
    #pragma unroll
    for (int i = 0; i < 4; ++i) {   // coalesced read of src[k][h]
      int kl = i * 16 + n;
      float4 v = *(const float4*)&src[(size_t)(kt * 64 + kl) * 128 + ht * 64 + m * 4];
      tile[kl][m * 4 + 0] = v.x;
      tile[kl][m * 4 + 1] = v.y;
      tile[kl][m * 4 + 2] = v.z;
      tile[kl][m * 4 + 3] = v.w;
    }
    __syncthreads();
    #pragma unroll
    for (int i = 0; i < 4; ++i) {   // write WT2 unit rows (stride 72)
      int hl = i * 16 + n;
      size_t base = ((size_t)(e * 4 + kt) * 128 + ht * 64 + hl) * 72;
      ushort4 o;
      o.x = f2bf(tile[m * 4 + 0][hl]);
      o.y = f2bf(tile[m * 4 + 1][hl]);
      o.z = f2bf(tile[m * 4 + 2][hl]);
      o.w = f2bf(tile[m * 4 + 3][hl]);
      *(ushort4*)&WT2[base + m * 4] = o;
      if (m < 2) {                  // zero the 8-elem row pad
        ushort4 z = {0, 0, 0, 0};
        *(ushort4*)&WT2[base + 64 + m * 4] = z;
      }
    }
  } else {
    // gate weights WgT[n][256], n = t*8+g
    unsigned short* WgT = WT2 + WGT_OFF;
    #pragma unroll
    for (int it = 0; it < 16; ++it) {
      int j = it * 256 + tid;
      int n = j >> 8, k = j & 255;
      int t = n >> 3, g = n & 7;
      WgT[j] = f2bf(Wg[(size_t)(t * 256 + k) * 8 + g]);
    }
  }
}

// ---------------------------------------------------------------------------
__global__ __launch_bounds__(256, 3)
void dmoe_main(const float* __restrict__ x,
               const unsigned short* __restrict__ WT2,
               const float* __restrict__ b_share,
               const float* __restrict__ b_task,
               const float* __restrict__ b_gate,
               float* __restrict__ out) {
  __shared__ unsigned short Bs0[UNIT_B / 2];   // 18432 B
  __shared__ unsigned short Bs1[UNIT_B / 2];   // 18432 B
  __shared__ float gates[8 * 68];              // [gate-col][row(64)+pad]

  const int tid  = threadIdx.x;
  const int lane = tid & 63;
  const int w    = tid >> 6;    // wave 0..3
  const int col  = lane & 15;
  const int quad = lane >> 4;
  const int mg   = w & 1;       // row half: [mg*32, mg*32+32)
  const int ng   = w >> 1;      // h half:   [ng*64, ng*64+64)
  const int blk  = blockIdx.x;
  const int t    = blk & 1;     // task
  const int rt   = blk >> 1;    // row tile (64 rows)
  const int rot  = (blk >> 3) & 7;
  const int hb   = ng * 64;

  const char* WT2b = (const char*)WT2;

  // ---- prologue: issue stage(unit0) loads first (longest latency) ----
  const int sr0 = rot;                       // slot 0 after rotation
  const int e0  = slot2e(sr0, t);
  uint4 p0, p1, p2, p3; uint2 p4;
  {
    const char* g = WT2b + (size_t)(e0 * 4 + 0) * UNIT_B + w * WAVE_B;
    p0 = *(const uint4*)(g + lane * 16);
    p1 = *(const uint4*)(g + 1024 + lane * 16);
    p2 = *(const uint4*)(g + 2048 + lane * 16);
    p3 = *(const uint4*)(g + 3072 + lane * 16);
    p4 = *(const uint2*)(g + 4096 + lane * 8);
  }

  // ---- A-fragments: 2 m-tiles x 8 k-steps resident ----
  short8 A[2][8];
  {
    const float* xb = x + ((size_t)rt * 64 + mg * 32 + col) * 256 + quad * 8;
    #pragma unroll
    for (int mt = 0; mt < 2; ++mt) {
      const float* xr = xb + (size_t)mt * 16 * 256;
      #pragma unroll
      for (int k = 0; k < 8; ++k) {
        float4 u = *(const float4*)(xr + k * 32);
        float4 v = *(const float4*)(xr + k * 32 + 4);
        short8 fr;
        fr[0] = (short)f2bf(u.x); fr[1] = (short)f2bf(u.y);
        fr[2] = (short)f2bf(u.z); fr[3] = (short)f2bf(u.w);
        fr[4] = (short)f2bf(v.x); fr[5] = (short)f2bf(v.y);
        fr[6] = (short)f2bf(v.z); fr[7] = (short)f2bf(v.w);
        A[mt][k] = fr;
      }
    }
  }

  // ---- gates for this task (ng==0 waves write; both compute) ----
  {
    const unsigned short* WgT = WT2 + WGT_OFF;
    int gr = (col < 8) ? col : 7;
    const unsigned short* bp = WgT + (size_t)(t * 8 + gr) * 256 + quad * 8;
    short8 Bg[8];
    #pragma unroll
    for (int k = 0; k < 8; ++k) Bg[k] = *(const short8*)(bp + k * 32);
    float bg = b_gate[t * 8 + gr];
    #pragma unroll
    for (int mt = 0; mt < 2; ++mt) {
      float4v ag = {0.f, 0.f, 0.f, 0.f};
      #pragma unroll
      for (int k = 0; k < 8; ++k)
        ag = __builtin_amdgcn_mfma_f32_16x16x32_bf16(A[mt][k], Bg[k], ag, 0, 0, 0);
      #pragma unroll
      for (int r = 0; r < 4; ++r) {
        float vlog = ag[r] + bg;
        float m = vlog;
        m = fmaxf(m, __shfl_xor(m, 1));
        m = fmaxf(m, __shfl_xor(m, 2));
        m = fmaxf(m, __shfl_xor(m, 4));
        float p = __expf(vlog - m);
        float s = p;
        s += __shfl_xor(s, 1);
        s += __shfl_xor(s, 2);
        s += __shfl_xor(s, 4);
        if (ng == 0 && col < 8)
          gates[col * 68 + mg * 32 + mt * 16 + quad * 4 + r] = p / s;
      }
    }
  }

  // ---- write staged unit0 into Bs0 ----
  {
    char* l = (char*)Bs0 + w * WAVE_B;
    *(uint4*)(l + lane * 16)        = p0;
    *(uint4*)(l + 1024 + lane * 16) = p1;
    *(uint4*)(l + 2048 + lane * 16) = p2;
    *(uint4*)(l + 3072 + lane * 16) = p3;
    *(uint2*)(l + 4096 + lane * 8)  = p4;
  }
  __syncthreads();

  // ---- accumulators ----
  float tw[2][4][4];   // [mt][nt][r], task-local
  #pragma unroll
  for (int mt = 0; mt < 2; ++mt)
    #pragma unroll
    for (int nt = 0; nt < 4; ++nt)
      #pragma unroll
      for (int r = 0; r < 4; ++r)
        tw[mt][nt][r] = 0.f;

  // ---- slot loop: 8 experts x 4 k-units ----
  #pragma unroll 1
  for (int s = 0; s < 8; ++s) {
    const int sr  = (s + rot) & 7;
    const int e   = slot2e(sr, t);
    const int gc  = sr;                       // gate column
    const int sr2 = (s + 1 + rot) & 7;
    const int e2  = slot2e(sr2, t);           // next slot's expert
    const float* bp = (sr < 4) ? (b_share + sr * 128)
                               : (b_task + (size_t)(t * 4 + (sr - 4)) * 128);
    float bias[4];
    #pragma unroll
    for (int nt = 0; nt < 4; ++nt) bias[nt] = bp[hb + nt * 16 + col];

    float4v acc[2][4];
    #pragma unroll
    for (int mt = 0; mt < 2; ++mt)
      #pragma unroll
      for (int nt = 0; nt < 4; ++nt)
        acc[mt][nt] = (float4v){0.f, 0.f, 0.f, 0.f};

    #pragma unroll
    for (int kq = 0; kq < 4; ++kq) {
      // prefetch next unit (issued before compute for latency overlap)
      const bool doStage = !(s == 7 && kq == 3);
      const int  en  = (kq < 3) ? e : e2;
      const int  kqn = (kq + 1) & 3;
      uint4 q0, q1, q2, q3; uint2 q4;
      if (doStage) {
        const char* g = WT2b + (size_t)(en * 4 + kqn) * UNIT_B + w * WAVE_B;
        q0 = *(const uint4*)(g + lane * 16);
        q1 = *(const uint4*)(g + 1024 + lane * 16);
        q2 = *(const uint4*)(g + 2048 + lane * 16);
        q3 = *(const uint4*)(g + 3072 + lane * 16);
        q4 = *(const uint2*)(g + 4096 + lane * 8);
      }
      // compute unit (s, kq) from buffer kq&1
      {
        const char* Bb = (const char*)((kq & 1) ? Bs1 : Bs0);
        #pragma unroll
        for (int kk = 0; kk < 2; ++kk) {
          #pragma unroll
          for (int nt = 0; nt < 4; ++nt) {
            short8 bfr = *(const short8*)(Bb + (hb + nt * 16 + col) * ROW_B
                                          + kk * 64 + quad * 16);
            acc[0][nt] = __builtin_amdgcn_mfma_f32_16x16x32_bf16(
                A[0][kq * 2 + kk], bfr, acc[0][nt], 0, 0, 0);
            acc[1][nt] = __builtin_amdgcn_mfma_f32_16x16x32_bf16(
                A[1][kq * 2 + kk], bfr, acc[1][nt], 0, 0, 0);
          }
        }
      }
      // deposit prefetched unit into the other buffer
      if (doStage) {
        char* l = (char*)((kq & 1) ? Bs0 : Bs1) + w * WAVE_B;
        *(uint4*)(l + lane * 16)        = q0;
        *(uint4*)(l + 1024 + lane * 16) = q1;
        *(uint4*)(l + 2048 + lane * 16) = q2;
        *(uint4*)(l + 3072 + lane * 16) = q3;
        *(uint2*)(l + 4096 + lane * 8)  = q4;
      }
      // epilogue on last k-unit of the expert
      if (kq == 3) {
        #pragma unroll
        for (int mt = 0; mt < 2; ++mt) {
          float4 gv = *(const float4*)&gates[gc * 68 + mg * 32 + mt * 16 + quad * 4];
          #pragma unroll
          for (int nt = 0; nt < 4; ++nt)
            #pragma unroll
            for (int r = 0; r < 4; ++r) {
              float v = fmaxf(acc[mt][nt][r] + bias[nt], 0.f);
              tw[mt][nt][r] += ((const float*)&gv)[r] * v;
            }
        }
      }
      __syncthreads();
    }
  }

  // ---- write towers: out[t][row][h] ----
  #pragma unroll
  for (int mt = 0; mt < 2; ++mt)
    #pragma unroll
    for (int r = 0; r < 4; ++r) {
      size_t row = (size_t)rt * 64 + mg * 32 + mt * 16 + quad * 4 + r;
      float* op = out + ((size_t)t << 22) + row * 128 + hb;
      #pragma unroll
      for (int nt = 0; nt < 4; ++nt)
        op[nt * 16 + col] = tw[mt][nt][r];
    }
}

// ---------------------------------------------------------------------------
extern "C" void kernel_launch(void* const* d_in, const int* in_sizes, int n_in,
                              void* d_out, int out_size, void* d_ws, size_t ws_size,
                              hipStream_t stream) {
  const float* x       = (const float*)d_in[0];
  const float* W_share = (const float*)d_in[1];
  const float* b_share = (const float*)d_in[2];
  const float* W_task  = (const float*)d_in[3];
  const float* b_task  = (const float*)d_in[4];
  const float* W_gate  = (const float*)d_in[5];
  const float* b_gate  = (const float*)d_in[6];
  float* out = (float*)d_out;
  unsigned short* WT2 = (unsigned short*)d_ws;   // 884736 + 8192 B = 892928 B

  prep_kernel<<<97, 256, 0, stream>>>(W_share, W_task, W_gate, WT2);
  dmoe_main<<<1024, 256, 0, stream>>>(x, WT2, b_share, b_task, b_gate, out);
}